// Round 5
// baseline (119.090 us; speedup 1.0000x reference)
//
#include <hip/hip_runtime.h>

#define BATCH 512
#define SEQ   512
#define VOCAB 1000
#define EMB   100
#define UNITS 64
#define SC    2.88539008177792681f   // 2*log2(e): v_exp_f32(SC*s) == e^{2s}

typedef float v2f __attribute__((ext_vector_type(2)));

// ---------------------------------------------------------------------------
// Kernel 1: P[v][u] = SC*(sum_d emb[v][d] * Wxh[d][u] + b[u])   (VOCAB x UNITS)
// ---------------------------------------------------------------------------
__global__ __launch_bounds__(64) void proj_kernel(
    const float* __restrict__ emb, const float* __restrict__ Wxh,
    const float* __restrict__ bias, float* __restrict__ P) {
  const int v = blockIdx.x;
  const int u = threadIdx.x;
  const float* e = emb + v * EMB;
  float acc = bias[u];
#pragma unroll 5
  for (int d = 0; d < EMB; ++d) acc += e[d] * Wxh[d * UNITS + u];
  P[v * UNITS + u] = SC * acc;
}

// ---------------------------------------------------------------------------
// DPP all-gather of one value/lane across the lane's own 16-lane row.
// Slot->source-lane permutation calibrated at runtime on lane_id.
// ---------------------------------------------------------------------------
#define DPP_I(src, ctrl) __builtin_amdgcn_update_dpp(0, (src), (ctrl), 0xF, 0xF, true)

#define GATHER_ROW(v_, g_)                                          \
  do {                                                              \
    g_[0] = DPP_I((v_), 0x00);  /* quad_perm:[0,0,0,0] */           \
    g_[1] = DPP_I((v_), 0x55);  /* quad_perm:[1,1,1,1] */           \
    g_[2] = DPP_I((v_), 0xAA);  /* quad_perm:[2,2,2,2] */           \
    g_[3] = DPP_I((v_), 0xFF);  /* quad_perm:[3,3,3,3] */           \
    g_[4]  = DPP_I(g_[0], 0x124); g_[5]  = DPP_I(g_[1], 0x124);     \
    g_[6]  = DPP_I(g_[2], 0x124); g_[7]  = DPP_I(g_[3], 0x124);     \
    g_[8]  = DPP_I(g_[0], 0x128); g_[9]  = DPP_I(g_[1], 0x128);     \
    g_[10] = DPP_I(g_[2], 0x128); g_[11] = DPP_I(g_[3], 0x128);     \
    g_[12] = DPP_I(g_[0], 0x12C); g_[13] = DPP_I(g_[1], 0x12C);     \
    g_[14] = DPP_I(g_[2], 0x12C); g_[15] = DPP_I(g_[3], 0x12C);     \
  } while (0)

// Selection-free combine: permlaneN_swap exchanges complementary N-lane
// blocks between its two operands; the sum of BOTH outputs equals
// q_w[l] + q_w[l^N] where w alternates with lane parity. The weight layout
// (column bit4/bit5 = slot ^ F16/F32, calibrated) makes that exactly the
// lane's own-column sum. Non-volatile: scheduler may interleave freely.
__device__ __forceinline__ float swadd16(float vd, float vs) {
  int x = __float_as_int(vd), y = __float_as_int(vs);
  asm("s_nop 1\n\tv_permlane16_swap_b32 %0, %1" : "+v"(x), "+v"(y));
  return __int_as_float(x) + __int_as_float(y);
}
__device__ __forceinline__ float swadd32(float vd, float vs) {
  int x = __float_as_int(vd), y = __float_as_int(vs);
  asm("s_nop 1\n\tv_permlane32_swap_b32 %0, %1" : "+v"(x), "+v"(y));
  return __int_as_float(x) + __int_as_float(y);
}

// ---------------------------------------------------------------------------
// Kernel 2: sequential scan, one row per wave. Register-only h-broadcast.
// Per step: 16 DPP gather -> 32 pk_fma (8 accs, 4-deep) -> 4 pk_add +
// 4 extract-adds -> swap16+add x2 -> swap32+add -> exp -> add -> rcp -> fma.
// ---------------------------------------------------------------------------
__global__ __launch_bounds__(64)
__attribute__((amdgpu_waves_per_eu(1, 1)))
void scan_kernel(
    const int* __restrict__ tok, const float* __restrict__ P,
    const float* __restrict__ Whh, const float* __restrict__ Wout,
    const float* __restrict__ bout, float* __restrict__ out) {
  const int row  = blockIdx.x;
  const int lane = threadIdx.x;

  // ---- calibration: gather permutation ----
  int gcal[16];
  GATHER_ROW(lane, gcal);  // gcal[s] = source lane (== unit index) of slot s

  // ---- calibration: swap convention flags F16/F32 ----
  // Probe with vdst=lane, src0=1000+lane. Under convention A
  // (vdst'[even blk] = src0[odd blk]) the vdst output holds a >=1000 value
  // exactly on even blocks; under B, on odd blocks. F=0 for A, 1 for B.
  int pa16 = lane, pb16 = 1000 + lane;
  asm("s_nop 1\n\tv_permlane16_swap_b32 %0, %1" : "+v"(pa16), "+v"(pb16));
  const int b4 = (lane >> 4) & 1;
  const int F16 = (((pa16 >= 1000) ? 1 : 0) ^ b4) ? 0 : 1;

  int pa32 = lane, pb32 = 1000 + lane;
  asm("s_nop 1\n\tv_permlane32_swap_b32 %0, %1" : "+v"(pa32), "+v"(pb32));
  const int b5 = (lane >> 5) & 1;
  const int F32 = (((pa32 >= 1000) ? 1 : 0) ^ b5) ? 0 : 1;

  // ---- a-fold masks: lane l folds a (column l) into partial (j*,k*) with
  // j* = b4^F16, k* = b5^F32 (the slot whose column equals l). ----
  const int jstar = b4 ^ F16, kstar = b5 ^ F32;
  const int m00 = (jstar == 0 && kstar == 0) ? ~0 : 0;
  const int m01 = (jstar == 0 && kstar == 1) ? ~0 : 0;
  const int m10 = (jstar == 1 && kstar == 0) ? ~0 : 0;
  const int m11 = (jstar == 1 && kstar == 1) ? ~0 : 0;

  // ---- weights: partial (j,k) carries column (lane&15)|((j^F16)<<4)|
  // ((k^F32)<<5), rows permuted to gather order, pre-scaled by SC ----
  const int cb = lane & 15;
  const int c00 = cb | ((0 ^ F16) << 4) | ((0 ^ F32) << 5);
  const int c01 = cb | ((0 ^ F16) << 4) | ((1 ^ F32) << 5);
  const int c10 = cb | ((1 ^ F16) << 4) | ((0 ^ F32) << 5);
  const int c11 = cb | ((1 ^ F16) << 4) | ((1 ^ F32) << 5);
  v2f w00[8], w01[8], w10[8], w11[8];
#pragma unroll
  for (int s = 0; s < 8; ++s) {
    const int i0 = gcal[2 * s] * UNITS, i1 = gcal[2 * s + 1] * UNITS;
    float t00 = SC * Whh[i0 + c00], t01 = SC * Whh[i1 + c00];
    float t10 = SC * Whh[i0 + c01], t11 = SC * Whh[i1 + c01];
    float t20 = SC * Whh[i0 + c10], t21 = SC * Whh[i1 + c10];
    float t30 = SC * Whh[i0 + c11], t31 = SC * Whh[i1 + c11];
    asm volatile("" : "+v"(t00), "+v"(t01), "+v"(t10), "+v"(t11));
    asm volatile("" : "+v"(t20), "+v"(t21), "+v"(t30), "+v"(t31));
    w00[s].x = t00; w00[s].y = t01;  w01[s].x = t10; w01[s].y = t11;
    w10[s].x = t20; w10[s].y = t21;  w11[s].x = t30; w11[s].y = t31;
  }

  // ---- all 512 tokens of this row, pre-scaled by UNITS (coalesced) ----
  int tokv[SEQ / 64];
  const int* trow = tok + (long)row * SEQ;
#pragma unroll
  for (int c = 0; c < SEQ / 64; ++c) {
    int t = trow[c * 64 + lane] * UNITS;
    asm volatile("" : "+v"(t));
    tokv[c] = t;
  }

  float h = 0.f;

  // distance-2 P prefetch ring.
  float a0 = P[(long)__builtin_amdgcn_readlane(tokv[0], 0) + lane];
  float a1 = P[(long)__builtin_amdgcn_readlane(tokv[0], 1) + lane];

#pragma unroll
  for (int c = 0; c < SEQ / 64; ++c) {
#pragma unroll 2
    for (int tt = 0; tt < 64; ++tt) {
      float a_cur = a0;
      a0 = a1;
      int tkn = __builtin_amdgcn_readlane(tokv[c], (tt + 2) & 63);
      a1 = P[(long)tkn + lane];  // early rows of chunk at tt=62,63; patched below

      // ---- in-register all-gather of h across own 16-lane row ----
      int gi[16];
      GATHER_ROW(__float_as_int(h), gi);

      // ---- 4 parity-assigned partials, 8 accumulators (4-deep chains);
      // a_cur folded into the lane's parity-matched partial via bitmask ----
      const int ab = __float_as_int(a_cur);
      v2f q00A, q01A, q10A, q11A;
      v2f q00B = {0.f, 0.f}, q01B = {0.f, 0.f};
      v2f q10B = {0.f, 0.f}, q11B = {0.f, 0.f};
      q00A.x = __int_as_float(ab & m00); q00A.y = 0.f;
      q01A.x = __int_as_float(ab & m01); q01A.y = 0.f;
      q10A.x = __int_as_float(ab & m10); q10A.y = 0.f;
      q11A.x = __int_as_float(ab & m11); q11A.y = 0.f;
#pragma unroll
      for (int s = 0; s < 8; ++s) {
        v2f gp;
        gp.x = __int_as_float(gi[2 * s]);
        gp.y = __int_as_float(gi[2 * s + 1]);
        if (s & 1) {
          q00B += gp * w00[s]; q01B += gp * w01[s];
          q10B += gp * w10[s]; q11B += gp * w11[s];
        } else {
          q00A += gp * w00[s]; q01A += gp * w01[s];
          q10A += gp * w10[s]; q11A += gp * w11[s];
        }
      }
      v2f r00 = q00A + q00B, r01 = q01A + q01B;
      v2f r10 = q10A + q10B, r11 = q11A + q11B;
      float p00 = r00.x + r00.y;   // partial (j=0,k=0)
      float p01 = r01.x + r01.y;   // partial (j=0,k=1)
      float p10 = r10.x + r10.y;   // partial (j=1,k=0)
      float p11 = r11.x + r11.y;   // partial (j=1,k=1)

      // ---- selection-free combine (vdst slot = j/k = 1) ----
      float g0 = swadd16(p10, p00);   // halfsum, col bit5 = 0^F32
      float g1 = swadd16(p11, p01);   // halfsum, col bit5 = 1^F32
      float yv = swadd32(g1, g0);     // full own-column sum (= SC * s + a)

      // tanh(s) = 1 - 2/(e^{2s}+1);  e^{2s} = 2^yv (SC prescale)
      float ex; asm("v_exp_f32 %0, %1\n\ts_nop 1" : "=v"(ex) : "v"(yv));
      float t1 = ex + 1.f;
      float rc; asm("v_rcp_f32 %0, %1\n\ts_nop 1" : "=v"(rc) : "v"(t1));
      h = __builtin_fmaf(-2.f, rc, 1.f);
    }
    if (c + 1 < SEQ / 64) {  // restore ring invariant for next chunk
      a0 = P[(long)__builtin_amdgcn_readlane(tokv[c + 1], 0) + lane];
      a1 = P[(long)__builtin_amdgcn_readlane(tokv[c + 1], 1) + lane];
    }
  }

  // out[row] = sigmoid(sum_j h[j]*Wout[j] + bout)
  float p = h * Wout[lane];
#pragma unroll
  for (int off = 32; off > 0; off >>= 1) p += __shfl_xor(p, off);
  if (lane == 0) out[row] = 1.f / (1.f + __expf(-(p + bout[0])));
}

extern "C" void kernel_launch(void* const* d_in, const int* in_sizes, int n_in,
                              void* d_out, int out_size, void* d_ws, size_t ws_size,
                              hipStream_t stream) {
  const int*   tok  = (const int*)  d_in[0];  // [BATCH, SEQ] int32
  const float* emb  = (const float*)d_in[1];  // [VOCAB, EMB]
  const float* Wxh  = (const float*)d_in[2];  // [EMB, UNITS]
  const float* Whh  = (const float*)d_in[3];  // [UNITS, UNITS]
  const float* bias = (const float*)d_in[4];  // [UNITS]
  const float* Wout = (const float*)d_in[5];  // [UNITS, 1]
  const float* bout = (const float*)d_in[6];  // [1]
  float* out = (float*)d_out;                 // [BATCH, 1] fp32

  float* P = (float*)d_ws;                    // VOCAB*UNITS fp32 = 256 KB

  proj_kernel<<<VOCAB, 64, 0, stream>>>(emb, Wxh, bias, P);
  scan_kernel<<<BATCH, 64, 0, stream>>>(tok, P, Whh, Wout, bout, out);
}

// Round 6
// 99.475 us; speedup vs baseline: 1.1972x; 1.1972x over previous
//
#include <hip/hip_runtime.h>

#define BATCH 512
#define SEQ   512
#define VOCAB 1000
#define EMB   100
#define UNITS 64
#define SC    2.88539008177792681f   // 2*log2(e): v_exp_f32(SC*s) == e^{2s}

typedef float v2f __attribute__((ext_vector_type(2)));

// ---------------------------------------------------------------------------
// Kernel 1: P[v][u] = SC*( (emb[v]@Wxh)[u] + b[u] + colsum(Whh)[u] )
// The colsum fold supports the r-recurrence in the scan:
//   y = x + W.h, h = 1-2r  =>  y = (x + W.1) - 2*W.r
// so the scan only needs r and weights -2*SC*W; the per-step h=fma(-2,r,1)
// disappears from the serial loop.
// ---------------------------------------------------------------------------
__global__ __launch_bounds__(64) void proj_kernel(
    const float* __restrict__ emb, const float* __restrict__ Wxh,
    const float* __restrict__ bias, const float* __restrict__ Whh,
    float* __restrict__ P) {
  const int v = blockIdx.x;
  const int u = threadIdx.x;
  const float* e = emb + v * EMB;
  float acc = bias[u];
#pragma unroll 5
  for (int d = 0; d < EMB; ++d) acc += e[d] * Wxh[d * UNITS + u];
  float csum = 0.f;
#pragma unroll 8
  for (int i = 0; i < UNITS; ++i) csum += Whh[i * UNITS + u];
  P[v * UNITS + u] = SC * (acc + csum);
}

// ---------------------------------------------------------------------------
// DPP all-gather of one value/lane across the lane's own 16-lane row.
// Slot->source-lane permutation calibrated at runtime on lane_id.
// ---------------------------------------------------------------------------
#define DPP_I(src, ctrl) __builtin_amdgcn_update_dpp(0, (src), (ctrl), 0xF, 0xF, true)

#define GATHER_ROW(v_, g_)                                          \
  do {                                                              \
    g_[0] = DPP_I((v_), 0x00);  /* quad_perm:[0,0,0,0] */           \
    g_[1] = DPP_I((v_), 0x55);  /* quad_perm:[1,1,1,1] */           \
    g_[2] = DPP_I((v_), 0xAA);  /* quad_perm:[2,2,2,2] */           \
    g_[3] = DPP_I((v_), 0xFF);  /* quad_perm:[3,3,3,3] */           \
    g_[4]  = DPP_I(g_[0], 0x124); g_[5]  = DPP_I(g_[1], 0x124);     \
    g_[6]  = DPP_I(g_[2], 0x124); g_[7]  = DPP_I(g_[3], 0x124);     \
    g_[8]  = DPP_I(g_[0], 0x128); g_[9]  = DPP_I(g_[1], 0x128);     \
    g_[10] = DPP_I(g_[2], 0x128); g_[11] = DPP_I(g_[3], 0x128);     \
    g_[12] = DPP_I(g_[0], 0x12C); g_[13] = DPP_I(g_[1], 0x12C);     \
    g_[14] = DPP_I(g_[2], 0x12C); g_[15] = DPP_I(g_[3], 0x12C);     \
  } while (0)

// lane^16 / lane^32 exchange (r4-proven form: duplicate, swap, cndmask-select).
__device__ __forceinline__ float sw16(float v, bool sel) {
  int x = __float_as_int(v), y = x;
  asm volatile("s_nop 1\n\tv_permlane16_swap_b32 %0, %1" : "+v"(x), "+v"(y));
  return sel ? __int_as_float(x) : __int_as_float(y);
}
__device__ __forceinline__ float sw32(float v, bool sel) {
  int x = __float_as_int(v), y = x;
  asm volatile("s_nop 1\n\tv_permlane32_swap_b32 %0, %1" : "+v"(x), "+v"(y));
  return sel ? __int_as_float(x) : __int_as_float(y);
}

// ---------------------------------------------------------------------------
// Kernel 2: sequential scan on r(t) = 1/(e^{2s}+1), one row per wave.
// Wall time = 512 x per-step instruction walk (single-wave issue cadence
// ~5.3 cyc/instr, r2-calibrated), so every instruction removed counts.
// Per step (~73 ops): 16 DPP gather -> 32 pk_fma (4 accs, 8-deep, -2SC
// folded into weights, P' folded into acc0 init) -> 4 extract adds ->
// r4 combine (2x sw16 + sw32) -> v_exp -> add -> rcp.
// ---------------------------------------------------------------------------
__global__ __launch_bounds__(64)
__attribute__((amdgpu_waves_per_eu(1, 1)))
void scan_kernel(
    const int* __restrict__ tok, const float* __restrict__ P,
    const float* __restrict__ Whh, const float* __restrict__ Wout,
    const float* __restrict__ bout, float* __restrict__ out) {
  const int row  = blockIdx.x;
  const int lane = threadIdx.x;

  // ---- calibration: gather permutation + swap register-select ----
  int gcal[16];
  GATHER_ROW(lane, gcal);  // gcal[s] = source lane (== unit index) of slot s

  int x16 = lane, y16 = lane;
  asm volatile("s_nop 1\n\tv_permlane16_swap_b32 %0, %1" : "+v"(x16), "+v"(y16));
  const bool sel16 = (x16 == (lane ^ 16));
  int x32 = lane, y32 = lane;
  asm volatile("s_nop 1\n\tv_permlane32_swap_b32 %0, %1" : "+v"(x32), "+v"(y32));
  const bool sel32 = (x32 == (lane ^ 32));

  // ---- weights: 4 columns (lane, ^16, ^32, ^48) x own-row 16 inputs,
  // permuted to gather order, scaled by -2*SC (r-recurrence), pinned ----
  const int c0 = lane, c1 = lane ^ 16, c2 = lane ^ 32, c3 = lane ^ 48;
  v2f w0[8], w1[8], w2[8], w3[8];
#pragma unroll
  for (int s = 0; s < 8; ++s) {
    const int i0 = gcal[2 * s] * UNITS, i1 = gcal[2 * s + 1] * UNITS;
    float t00 = -2.f * SC * Whh[i0 + c0], t01 = -2.f * SC * Whh[i1 + c0];
    float t10 = -2.f * SC * Whh[i0 + c1], t11 = -2.f * SC * Whh[i1 + c1];
    float t20 = -2.f * SC * Whh[i0 + c2], t21 = -2.f * SC * Whh[i1 + c2];
    float t30 = -2.f * SC * Whh[i0 + c3], t31 = -2.f * SC * Whh[i1 + c3];
    asm volatile("" : "+v"(t00), "+v"(t01), "+v"(t10), "+v"(t11));
    asm volatile("" : "+v"(t20), "+v"(t21), "+v"(t30), "+v"(t31));
    w0[s].x = t00; w0[s].y = t01;  w1[s].x = t10; w1[s].y = t11;
    w2[s].x = t20; w2[s].y = t21;  w3[s].x = t30; w3[s].y = t31;
  }

  // ---- all 512 tokens of this row, pre-scaled by UNITS (coalesced) ----
  int tokv[SEQ / 64];
  const int* trow = tok + (long)row * SEQ;
#pragma unroll
  for (int c = 0; c < SEQ / 64; ++c) {
    int t = trow[c * 64 + lane] * UNITS;
    asm volatile("" : "+v"(t));
    tokv[c] = t;
  }

  float r = 0.5f;  // h = 0  <=>  r = (1-h)/2 = 0.5

  // distance-2 P prefetch ring.
  float a0 = P[(long)__builtin_amdgcn_readlane(tokv[0], 0) + lane];
  float a1 = P[(long)__builtin_amdgcn_readlane(tokv[0], 1) + lane];

#pragma unroll
  for (int c = 0; c < SEQ / 64; ++c) {
#pragma unroll
    for (int tt = 0; tt < 64; ++tt) {  // FULL unroll: readlane lanes become
      float a_cur = a0;                // immediates, ring movs rename away
      a0 = a1;
      int tkn = __builtin_amdgcn_readlane(tokv[c], (tt + 2) & 63);
      a1 = P[(long)tkn + lane];  // wrong row at tt=62,63; patched below

      // ---- in-register all-gather of r across own 16-lane row ----
      int gi[16];
      GATHER_ROW(__float_as_int(r), gi);

      // ---- 4 column partials, 8-deep pk_fma chains; P' folded into
      // acc0 init; -2*SC folded into weights ----
      v2f acc0, acc1 = {0.f, 0.f}, acc2 = {0.f, 0.f}, acc3 = {0.f, 0.f};
      acc0.x = a_cur; acc0.y = 0.f;
#pragma unroll
      for (int s = 0; s < 8; ++s) {
        v2f gp;
        gp.x = __int_as_float(gi[2 * s]);
        gp.y = __int_as_float(gi[2 * s + 1]);
        acc0 += gp * w0[s];
        acc1 += gp * w1[s];
        acc2 += gp * w2[s];
        acc3 += gp * w3[s];
      }
      float p0 = acc0.x + acc0.y;   // col lane      (incl. a_cur)
      float p1 = acc1.x + acc1.y;   // col lane^16
      float p2 = acc2.x + acc2.y;   // col lane^32
      float p3 = acc3.x + acc3.y;   // col lane^48

      // combine: yv[j] = P0(j) + P1(j^16) + P2(j^32) + P3(j^48) = SC * s(t+1)
      float s1 = p0 + sw16(p1, sel16);
      float s2 = p2 + sw16(p3, sel16);
      float yv = s1 + sw32(s2, sel32);

      // r = 1/(e^{2s}+1);  e^{2s} = 2^yv. Trans ops are HW-interlocked.
      float ex; asm("v_exp_f32 %0, %1" : "=v"(ex) : "v"(yv));
      r = __builtin_amdgcn_rcpf(ex + 1.f);
    }
    if (c + 1 < SEQ / 64) {  // restore ring invariant for next chunk
      a0 = P[(long)__builtin_amdgcn_readlane(tokv[c + 1], 0) + lane];
      a1 = P[(long)__builtin_amdgcn_readlane(tokv[c + 1], 1) + lane];
    }
  }

  // h = 1 - 2r (once); out[row] = sigmoid(sum_j h[j]*Wout[j] + bout)
  float h = __builtin_fmaf(-2.f, r, 1.f);
  float p = h * Wout[lane];
#pragma unroll
  for (int off = 32; off > 0; off >>= 1) p += __shfl_xor(p, off);
  if (lane == 0) out[row] = 1.f / (1.f + __expf(-(p + bout[0])));
}

extern "C" void kernel_launch(void* const* d_in, const int* in_sizes, int n_in,
                              void* d_out, int out_size, void* d_ws, size_t ws_size,
                              hipStream_t stream) {
  const int*   tok  = (const int*)  d_in[0];  // [BATCH, SEQ] int32
  const float* emb  = (const float*)d_in[1];  // [VOCAB, EMB]
  const float* Wxh  = (const float*)d_in[2];  // [EMB, UNITS]
  const float* Whh  = (const float*)d_in[3];  // [UNITS, UNITS]
  const float* bias = (const float*)d_in[4];  // [UNITS]
  const float* Wout = (const float*)d_in[5];  // [UNITS, 1]
  const float* bout = (const float*)d_in[6];  // [1]
  float* out = (float*)d_out;                 // [BATCH, 1] fp32

  float* P = (float*)d_ws;                    // VOCAB*UNITS fp32 = 256 KB

  proj_kernel<<<VOCAB, 64, 0, stream>>>(emb, Wxh, bias, Whh, P);
  scan_kernel<<<BATCH, 64, 0, stream>>>(tok, P, Whh, Wout, bout, out);
}